// Round 10
// baseline (261.281 us; speedup 1.0000x reference)
//
#include <hip/hip_runtime.h>
#include <math.h>

#define LQ 512
#define CN 384
#define CE 128
#define CH 192
#define NG 12
#define PPG 16
#define FEAT 2112
#define NPROJ 1152
#define WLs 0.5773502691896258f

// ws float offsets
#define WS_RAW  0u         // [l][1152]: q(0..191) k(192..383) v(384..575) qv kv vv
#define WS_QVG  589824u    // [l][144]
#define WS_KVT  663552u    // [144][512]
#define WS_VVG  737280u    // [l][288]
#define WS_QN   884736u    // [l][12]
#define WS_KNT  890880u    // [12][512]
#define WS_KT   897024u    // [192][512]
#define WS_ATT  995328u    // [i][j][12] unnormalized exp (no-max)
#define WS_FEAT 4141056u   // [i][2112]
#define WS_PART 5222400u   // [3][512][384] (k4/k5 only)
#define WS_PS2  5812224u   // [i][8][12] per-wave exp sums
#define WS_LGS  5861376u   // [i][j][12] base logits
#define WS_OEP  9007104u   // [i][8][12][128] partial O_Edge

// ---------------- K1a: tiled projection GEMM -> raw (+KT transposed copy) ----------------
__global__ __launch_bounds__(256) void k1a_gemm(
    const float* __restrict__ Node,
    const float* __restrict__ Wq, const float* __restrict__ Wk,
    const float* __restrict__ Wv, const float* __restrict__ Wqv,
    const float* __restrict__ Wkv, const float* __restrict__ Wvv,
    float* __restrict__ ws)
{
    __shared__ float As[64][68];
    __shared__ float Bs[64][48];
    const int tid = threadIdx.x;
    const int cb = blockIdx.x % 24;
    const int l0 = (blockIdx.x / 24) * 64;
    const int col0 = cb * 48;

    const float* W; int nc, lc0;
    if (col0 < 192)      { W = Wq;  nc = 192; lc0 = col0; }
    else if (col0 < 384) { W = Wk;  nc = 192; lc0 = col0 - 192; }
    else if (col0 < 576) { W = Wv;  nc = 192; lc0 = col0 - 384; }
    else if (col0 < 720) { W = Wqv; nc = 144; lc0 = col0 - 576; }
    else if (col0 < 864) { W = Wkv; nc = 144; lc0 = col0 - 720; }
    else                 { W = Wvv; nc = 288; lc0 = col0 - 864; }

    const int tx = tid & 15, ty = tid >> 4;
    float acc[4][3];
#pragma unroll
    for (int r = 0; r < 4; ++r)
#pragma unroll
        for (int c = 0; c < 3; ++c) acc[r][c] = 0.f;

    for (int kc = 0; kc < 6; ++kc) {
        __syncthreads();
#pragma unroll
        for (int pass = 0; pass < 4; ++pass) {
            int m = (tid >> 4) + pass * 16;
            int kk = (tid & 15) * 4;
            const float4 a = *(const float4*)(Node + (size_t)(l0 + m) * CN + kc * 64 + kk);
            As[kk + 0][m] = a.x; As[kk + 1][m] = a.y;
            As[kk + 2][m] = a.z; As[kk + 3][m] = a.w;
        }
#pragma unroll
        for (int p = 0; p < 12; ++p) {
            int idx = p * 256 + tid;
            int kk = idx / 48, c = idx - kk * 48;
            Bs[kk][c] = W[(size_t)(kc * 64 + kk) * nc + lc0 + c];
        }
        __syncthreads();
#pragma unroll 8
        for (int kk = 0; kk < 64; ++kk) {
            const float4 av = *(const float4*)&As[kk][tx * 4];
            const float b0 = Bs[kk][ty * 3 + 0];
            const float b1 = Bs[kk][ty * 3 + 1];
            const float b2 = Bs[kk][ty * 3 + 2];
            acc[0][0] = fmaf(av.x, b0, acc[0][0]); acc[0][1] = fmaf(av.x, b1, acc[0][1]); acc[0][2] = fmaf(av.x, b2, acc[0][2]);
            acc[1][0] = fmaf(av.y, b0, acc[1][0]); acc[1][1] = fmaf(av.y, b1, acc[1][1]); acc[1][2] = fmaf(av.y, b2, acc[1][2]);
            acc[2][0] = fmaf(av.z, b0, acc[2][0]); acc[2][1] = fmaf(av.z, b1, acc[2][1]); acc[2][2] = fmaf(av.z, b2, acc[2][2]);
            acc[3][0] = fmaf(av.w, b0, acc[3][0]); acc[3][1] = fmaf(av.w, b1, acc[3][1]); acc[3][2] = fmaf(av.w, b2, acc[3][2]);
        }
    }
    float* raw = ws + WS_RAW;
#pragma unroll
    for (int r = 0; r < 4; ++r)
#pragma unroll
        for (int c = 0; c < 3; ++c)
            raw[(size_t)(l0 + tx * 4 + r) * NPROJ + col0 + ty * 3 + c] = acc[r][c];
    if (col0 >= 192 && col0 < 384) {
#pragma unroll
        for (int r = 0; r < 4; ++r)
#pragma unroll
            for (int c = 0; c < 3; ++c)
                ws[WS_KT + (size_t)(col0 - 192 + ty * 3 + c) * LQ + l0 + tx * 4 + r] = acc[r][c];
    }
}

// ---------------- K1b: frame apply + point norms ----------------
__global__ __launch_bounds__(256) void k1b_vec(
    const float* __restrict__ rots, const float* __restrict__ trans,
    float* __restrict__ ws)
{
    __shared__ float sqbuf[96];
    const int tid = threadIdx.x;
    const int l = blockIdx.x;
    const float* raw = ws + WS_RAW + (size_t)l * NPROJ;

    if (tid < 192) {
        int src, pt, typ;
        if (tid < 48)      { typ = 0; pt = tid;      src = 576 + pt * 3; }
        else if (tid < 96) { typ = 1; pt = tid - 48; src = 720 + pt * 3; }
        else               { typ = 2; pt = tid - 96; src = 864 + pt * 3; }
        float v0 = raw[src], v1 = raw[src + 1], v2 = raw[src + 2];
        const float* R = rots + l * 9;
        float o0 = R[0] * v0 + R[1] * v1 + R[2] * v2 + trans[l * 3 + 0] * 0.1f;
        float o1 = R[3] * v0 + R[4] * v1 + R[5] * v2 + trans[l * 3 + 1] * 0.1f;
        float o2 = R[6] * v0 + R[7] * v1 + R[8] * v2 + trans[l * 3 + 2] * 0.1f;
        if (typ == 0) {
            float* dst = ws + WS_QVG + (size_t)l * 144 + pt * 3;
            dst[0] = o0; dst[1] = o1; dst[2] = o2;
        } else if (typ == 1) {
            ws[WS_KVT + (size_t)(pt * 3 + 0) * LQ + l] = o0;
            ws[WS_KVT + (size_t)(pt * 3 + 1) * LQ + l] = o1;
            ws[WS_KVT + (size_t)(pt * 3 + 2) * LQ + l] = o2;
        } else {
            float* dst = ws + WS_VVG + (size_t)l * 288 + pt * 3;
            dst[0] = o0; dst[1] = o1; dst[2] = o2;
        }
        if (tid < 96) sqbuf[tid] = o0 * o0 + o1 * o1 + o2 * o2;
    }
    __syncthreads();
    if (tid < 24) {
        int typ = tid / 12, g = tid % 12;
        int b = typ * 48 + g * 4;
        float s = sqbuf[b] + sqbuf[b + 1] + sqbuf[b + 2] + sqbuf[b + 3];
        if (typ == 0) ws[WS_QN + (size_t)l * 12 + g] = s;
        else          ws[WS_KNT + (size_t)g * LQ + l] = s;
    }
}

// ---------------- K2a: base logits -> LGS ----------------
__global__ __launch_bounds__(256) void k2a_logits(
    const float* __restrict__ gamma, float* __restrict__ ws)
{
    __shared__ float cgls[NG];
    const int tid = threadIdx.x;
    const int i = blockIdx.x >> 1;
    const int h = blockIdx.x & 1;
    const int j = h * 256 + tid;

    if (tid < NG)
        cgls[tid] = log1pf(__expf(gamma[tid])) * 0.11785113019775793f;
    __syncthreads();

    const float* qrow  = ws + WS_RAW + (size_t)i * NPROJ;
    const float* qvrow = ws + WS_QVG + (size_t)i * 144;
    const float* qnrow = ws + WS_QN  + (size_t)i * NG;
    const float* KT  = ws + WS_KT;
    const float* KVT = ws + WS_KVT;
    const float* KNT = ws + WS_KNT;
    float lgs[NG];
#pragma unroll
    for (int g = 0; g < NG; ++g) {
        float qk = 0.f;
#pragma unroll
        for (int u = 0; u < PPG; ++u)
            qk = fmaf(qrow[g * PPG + u], KT[(size_t)(g * PPG + u) * LQ + j], qk);
        float dt = 0.f;
#pragma unroll
        for (int u = 0; u < 12; ++u)
            dt = fmaf(qvrow[g * 12 + u], KVT[(size_t)(g * 12 + u) * LQ + j], dt);
        float sq = qnrow[g] + KNT[(size_t)g * LQ + j] - 2.f * dt;
        lgs[g] = qk * 0.25f - cgls[g] * sq;
    }
    float4* dst = (float4*)(ws + WS_LGS + ((size_t)i * LQ + j) * NG);
    float4 s0, s1, s2;
    s0.x = lgs[0]; s0.y = lgs[1]; s0.z = lgs[2];  s0.w = lgs[3];
    s1.x = lgs[4]; s1.y = lgs[5]; s1.z = lgs[6];  s1.w = lgs[7];
    s2.x = lgs[8]; s2.y = lgs[9]; s2.z = lgs[10]; s2.w = lgs[11];
    dst[0] = s0; dst[1] = s1; dst[2] = s2;
}

// ---------------- K2b: single Edge pass: bias + exp(no-max) + partial O_Edge ----------------
// Barrier-free. Wave w of block (i,h) sweeps rows j0..j0+63 (2 rows per float4 wave-load).
__global__ __launch_bounds__(256) void k2b_edge(
    const float* __restrict__ Edge, const float* __restrict__ Wbias,
    float* __restrict__ ws)
{
    const int tid = threadIdx.x;
    const int i = blockIdx.x >> 1;
    const int h = blockIdx.x & 1;
    const int w = tid >> 6, lane = tid & 63;
    const int half = lane >> 5, c4 = lane & 31;
    const int j0 = h * 256 + w * 64;

    // Wbias for this lane's 4 channels -> 48 registers
    float wb[4][NG];
#pragma unroll
    for (int r = 0; r < 4; ++r)
#pragma unroll
        for (int g = 0; g < NG; ++g)
            wb[r][g] = Wbias[(c4 * 4 + r) * NG + g];

    float oea[NG][4];
#pragma unroll
    for (int g = 0; g < NG; ++g)
#pragma unroll
        for (int r = 0; r < 4; ++r) oea[g][r] = 0.f;
    float ps[NG];
#pragma unroll
    for (int g = 0; g < NG; ++g) ps[g] = 0.f;

    const float* ebase = Edge + ((size_t)i * LQ + j0) * CE;
    const float* lgsb  = ws + WS_LGS + ((size_t)i * LQ + j0) * NG;
    float* attb        = ws + WS_ATT + ((size_t)i * LQ + j0) * NG;

    float4 cur = *(const float4*)(ebase + (size_t)half * CE + c4 * 4);
    for (int p = 0; p < 32; ++p) {
        float4 nxt;
        if (p < 31)
            nxt = *(const float4*)(ebase + (size_t)(2 * p + 2 + half) * CE + c4 * 4);
        // bias partial for this lane's 4 channels
        float b[NG];
#pragma unroll
        for (int g = 0; g < NG; ++g)
            b[g] = fmaf(cur.x, wb[0][g], fmaf(cur.y, wb[1][g],
                   fmaf(cur.z, wb[2][g], cur.w * wb[3][g])));
        // butterfly allreduce over the 32 lanes of this half
#pragma unroll
        for (int off = 1; off < 32; off <<= 1)
#pragma unroll
            for (int g = 0; g < NG; ++g) b[g] += __shfl_xor(b[g], off);
        // add base logits (broadcast read) and exponentiate (no max subtraction)
        const float4* lg4 = (const float4*)(lgsb + (size_t)(2 * p + half) * NG);
        float4 L0 = lg4[0], L1 = lg4[1], L2 = lg4[2];
        float e[NG];
        e[0] = __expf(WLs * (b[0] + L0.x)); e[1] = __expf(WLs * (b[1] + L0.y));
        e[2] = __expf(WLs * (b[2] + L0.z)); e[3] = __expf(WLs * (b[3] + L0.w));
        e[4] = __expf(WLs * (b[4] + L1.x)); e[5] = __expf(WLs * (b[5] + L1.y));
        e[6] = __expf(WLs * (b[6] + L1.z)); e[7] = __expf(WLs * (b[7] + L1.w));
        e[8] = __expf(WLs * (b[8] + L2.x)); e[9] = __expf(WLs * (b[9] + L2.y));
        e[10] = __expf(WLs * (b[10] + L2.z)); e[11] = __expf(WLs * (b[11] + L2.w));
#pragma unroll
        for (int g = 0; g < NG; ++g) {
            ps[g] += e[g];
            oea[g][0] = fmaf(e[g], cur.x, oea[g][0]);
            oea[g][1] = fmaf(e[g], cur.y, oea[g][1]);
            oea[g][2] = fmaf(e[g], cur.z, oea[g][2]);
            oea[g][3] = fmaf(e[g], cur.w, oea[g][3]);
        }
        if (c4 == 0) {
            float4 s0, s1, s2;
            s0.x = e[0]; s0.y = e[1]; s0.z = e[2];  s0.w = e[3];
            s1.x = e[4]; s1.y = e[5]; s1.z = e[6];  s1.w = e[7];
            s2.x = e[8]; s2.y = e[9]; s2.z = e[10]; s2.w = e[11];
            float4* d = (float4*)(attb + (size_t)(2 * p + half) * NG);
            d[0] = s0; d[1] = s1; d[2] = s2;
        }
        cur = nxt;
    }
    // combine halves
#pragma unroll
    for (int g = 0; g < NG; ++g) {
        ps[g] += __shfl_xor(ps[g], 32);
#pragma unroll
        for (int r = 0; r < 4; ++r) oea[g][r] += __shfl_xor(oea[g][r], 32);
    }
    const int wslot = h * 4 + w;
    if (lane == 0) {
        float* d = ws + WS_PS2 + ((size_t)i * 8 + wslot) * NG;
        float4 s0, s1, s2;
        s0.x = ps[0]; s0.y = ps[1]; s0.z = ps[2];  s0.w = ps[3];
        s1.x = ps[4]; s1.y = ps[5]; s1.z = ps[6];  s1.w = ps[7];
        s2.x = ps[8]; s2.y = ps[9]; s2.z = ps[10]; s2.w = ps[11];
        ((float4*)d)[0] = s0; ((float4*)d)[1] = s1; ((float4*)d)[2] = s2;
    }
    if (half == 0) {
        float* ob = ws + WS_OEP + ((size_t)(i * 8 + wslot) * NG) * CE;
#pragma unroll
        for (int g = 0; g < NG; ++g) {
            float4 v;
            v.x = oea[g][0]; v.y = oea[g][1]; v.z = oea[g][2]; v.w = oea[g][3];
            *(float4*)(ob + (size_t)g * CE + c4 * 4) = v;
        }
    }
}

// ---------------- K3b: O_Edge merge + O_Node / O_vec / O_norm -> feat ----------------
// grid 1024: (i = bid>>1, s = bid&1). s splits tasks & merge outputs.
__global__ __launch_bounds__(256) void k3b_out(
    const float* __restrict__ rots, const float* __restrict__ trans,
    float* __restrict__ ws)
{
    __shared__ float at[LQ][13];
    __shared__ float invl[NG];
    __shared__ float ovecl[240];
    const int tid = threadIdx.x;
    const int qi = blockIdx.x >> 1;
    const int s  = blockIdx.x & 1;

    if (tid < NG) {
        float t = 0.f;
        for (int w = 0; w < 8; ++w)
            t += ws[WS_PS2 + ((size_t)qi * 8 + w) * NG + tid];
        invl[tid] = 1.f / t;
    }
    __syncthreads();
    float inv[NG];
#pragma unroll
    for (int g = 0; g < NG; ++g) inv[g] = invl[g];

    // stage normalized attention (both blocks duplicate)
    const float* att = ws + WS_ATT + (size_t)qi * LQ * NG;
    for (int m = 0; m < 2; ++m) {
        int j = tid + m * 256;
        const float4* src = (const float4*)(att + (size_t)j * NG);
        float4 a = src[0], b = src[1], c = src[2];
        at[j][0] = a.x * inv[0]; at[j][1] = a.y * inv[1];
        at[j][2] = a.z * inv[2]; at[j][3] = a.w * inv[3];
        at[j][4] = b.x * inv[4]; at[j][5] = b.y * inv[5];
        at[j][6] = b.z * inv[6]; at[j][7] = b.w * inv[7];
        at[j][8] = c.x * inv[8]; at[j][9] = c.y * inv[9];
        at[j][10] = c.z * inv[10]; at[j][11] = c.w * inv[11];
    }

    // O_Edge merge: this block's 768 outputs
    float* feat = ws + WS_FEAT + (size_t)qi * FEAT;
    {
        const float* ob = ws + WS_OEP + (size_t)qi * 8 * NG * CE;
#pragma unroll
        for (int m = 0; m < 3; ++m) {
            int o = s * 768 + m * 256 + tid;
            float t = 0.f;
#pragma unroll
            for (int w = 0; w < 8; ++w) t += ob[(size_t)w * NG * CE + o];
            feat[o] = t * inv[o >> 7];
        }
    }
    __syncthreads();

    // Phase B: 240 tasks per block
    const float* raw = ws + WS_RAW;
    const float* vvg = ws + WS_VVG;
    if (tid < 240) {
        if (s == 0 && tid < 192) {
            int g = tid >> 4;
            float sum = 0.f;
#pragma unroll 4
            for (int j = 0; j < LQ; ++j)
                sum = fmaf(at[j][g], raw[(size_t)j * NPROJ + 384 + tid], sum);
            feat[1536 + tid] = sum;
        } else {
            int u = (s == 0) ? (tid - 192) : (48 + tid);   // global vv index
            int lidx = (s == 0) ? (tid - 192) : tid;       // local ovec index
            int g = u / 24;
            float sum = 0.f;
#pragma unroll 4
            for (int j = 0; j < LQ; ++j)
                sum = fmaf(at[j][g], vvg[(size_t)j * 288 + u], sum);
            ovecl[lidx] = sum;
        }
    }
    __syncthreads();

    // Phase C: inverse frame + norms for this block's points
    int npts = (s == 0) ? 16 : 80;
    if (tid < npts) {
        int P = (s == 0) ? tid : (16 + tid);
        int u0l = (s == 0) ? (P * 3) : (P * 3 - 48);
        const float* R = rots + qi * 9;
        float t0 = trans[qi * 3 + 0] * 0.1f;
        float t1 = trans[qi * 3 + 1] * 0.1f;
        float t2 = trans[qi * 3 + 2] * 0.1f;
        float d0 = ovecl[u0l + 0] - t0;
        float d1 = ovecl[u0l + 1] - t1;
        float d2 = ovecl[u0l + 2] - t2;
        float o0 = R[0] * d0 + R[3] * d1 + R[6] * d2;
        float o1 = R[1] * d0 + R[4] * d1 + R[7] * d2;
        float o2 = R[2] * d0 + R[5] * d1 + R[8] * d2;
        feat[1728 + P * 3 + 0] = o0;
        feat[1728 + P * 3 + 1] = o1;
        feat[1728 + P * 3 + 2] = o2;
        feat[2016 + P] = sqrtf(o0 * o0 + o1 * o1 + o2 * o2 + 1e-8f);
    }
}

// ---------------- K4: feat @ Wout — LDS-tiled GEMM, split-K x3 ----------------
__global__ __launch_bounds__(256) void k4_gemm(const float* __restrict__ Wout,
                                               float* __restrict__ ws)
{
    __shared__ float As[64][68];
    __shared__ float Bs[64][48];
    const int tid = threadIdx.x;
    const int cc = blockIdx.x >> 6;
    const int t  = blockIdx.x & 63;
    const int l0 = (t >> 3) * 64;
    const int col0 = (t & 7) * 48;
    const float* feat = ws + WS_FEAT;

    const int tx = tid & 15, ty = tid >> 4;
    float acc[4][3];
#pragma unroll
    for (int r = 0; r < 4; ++r)
#pragma unroll
        for (int c = 0; c < 3; ++c) acc[r][c] = 0.f;

    for (int kc = cc * 11; kc < cc * 11 + 11; ++kc) {
        __syncthreads();
#pragma unroll
        for (int pass = 0; pass < 4; ++pass) {
            int m = (tid >> 4) + pass * 16;
            int kk = (tid & 15) * 4;
            const float4 a = *(const float4*)(feat + (size_t)(l0 + m) * FEAT + kc * 64 + kk);
            As[kk + 0][m] = a.x; As[kk + 1][m] = a.y;
            As[kk + 2][m] = a.z; As[kk + 3][m] = a.w;
        }
#pragma unroll
        for (int p = 0; p < 12; ++p) {
            int idx = p * 256 + tid;
            int kk = idx / 48, c = idx - kk * 48;
            Bs[kk][c] = Wout[(size_t)(kc * 64 + kk) * CN + col0 + c];
        }
        __syncthreads();
#pragma unroll 8
        for (int kk = 0; kk < 64; ++kk) {
            const float4 av = *(const float4*)&As[kk][tx * 4];
            const float b0 = Bs[kk][ty * 3 + 0];
            const float b1 = Bs[kk][ty * 3 + 1];
            const float b2 = Bs[kk][ty * 3 + 2];
            acc[0][0] = fmaf(av.x, b0, acc[0][0]); acc[0][1] = fmaf(av.x, b1, acc[0][1]); acc[0][2] = fmaf(av.x, b2, acc[0][2]);
            acc[1][0] = fmaf(av.y, b0, acc[1][0]); acc[1][1] = fmaf(av.y, b1, acc[1][1]); acc[1][2] = fmaf(av.y, b2, acc[1][2]);
            acc[2][0] = fmaf(av.z, b0, acc[2][0]); acc[2][1] = fmaf(av.z, b1, acc[2][1]); acc[2][2] = fmaf(av.z, b2, acc[2][2]);
            acc[3][0] = fmaf(av.w, b0, acc[3][0]); acc[3][1] = fmaf(av.w, b1, acc[3][1]); acc[3][2] = fmaf(av.w, b2, acc[3][2]);
        }
    }
    float* part = ws + WS_PART + (size_t)cc * LQ * CN;
#pragma unroll
    for (int r = 0; r < 4; ++r)
#pragma unroll
        for (int c = 0; c < 3; ++c)
            part[(size_t)(l0 + tx * 4 + r) * CN + col0 + ty * 3 + c] = acc[r][c];
}

// ---------------- K5: reduce partials + bias ----------------
__global__ __launch_bounds__(384) void k5_red(const float* __restrict__ bout,
                                              const float* __restrict__ wsc,
                                              float* __restrict__ out)
{
    const int i = blockIdx.x, n = threadIdx.x;
    const float* part = wsc + WS_PART;
    size_t idx = (size_t)i * CN + n;
    size_t st = (size_t)LQ * CN;
    out[idx] = part[idx] + part[st + idx] + part[2 * st + idx] + bout[n];
}

extern "C" void kernel_launch(void* const* d_in, const int* in_sizes, int n_in,
                              void* d_out, int out_size, void* d_ws, size_t ws_size,
                              hipStream_t stream) {
    const float* Node  = (const float*)d_in[0];
    const float* Edge  = (const float*)d_in[1];
    const float* rots  = (const float*)d_in[2];
    const float* trans = (const float*)d_in[3];
    const float* Wq    = (const float*)d_in[4];
    const float* Wk    = (const float*)d_in[5];
    const float* Wv    = (const float*)d_in[6];
    const float* Wqv   = (const float*)d_in[7];
    const float* Wkv   = (const float*)d_in[8];
    const float* Wvv   = (const float*)d_in[9];
    const float* Wbias = (const float*)d_in[10];
    const float* gamma = (const float*)d_in[11];
    const float* Wout  = (const float*)d_in[12];
    const float* bout  = (const float*)d_in[13];
    float* ws = (float*)d_ws;

    k1a_gemm<<<192, 256, 0, stream>>>(Node, Wq, Wk, Wv, Wqv, Wkv, Wvv, ws);
    k1b_vec<<<512, 256, 0, stream>>>(rots, trans, ws);
    k2a_logits<<<1024, 256, 0, stream>>>(gamma, ws);
    k2b_edge<<<1024, 256, 0, stream>>>(Edge, Wbias, ws);
    k3b_out<<<1024, 256, 0, stream>>>(rots, trans, ws);
    k4_gemm<<<192, 256, 0, stream>>>(Wout, ws);
    k5_red<<<512, 384, 0, stream>>>(bout, ws, (float*)d_out);
}

// Round 11
// 208.011 us; speedup vs baseline: 1.2561x; 1.2561x over previous
//
#include <hip/hip_runtime.h>
#include <math.h>

#define LQ 512
#define CN 384
#define CE 128
#define CH 192
#define NG 12
#define PPG 16
#define FEAT 2112
#define NPROJ 1152
#define WLs 0.5773502691896258f

// ws float offsets
#define WS_RAW  0u         // [l][1152]
#define WS_QVG  589824u    // [l][144]
#define WS_KVT  663552u    // [144][512]
#define WS_VVG  737280u    // [l][288]
#define WS_QN   884736u    // [l][12]
#define WS_KNT  890880u    // [12][512]
#define WS_KT   897024u    // [192][512]
#define WS_ATT  995328u    // [i][12][512] TRANSPOSED unnormalized exp
#define WS_FEAT 4141056u   // [i][2112]
#define WS_PART 5222400u   // [3][512][384] (k4/k5 only)
#define WS_PM   5812224u   // [i][h][12] partial max
#define WS_PS   5824512u   // [i][h][12] partial sum
#define WS_LGS  5861376u   // [i][j][12] base logits

// ---------------- K1a: tiled projection GEMM -> raw (+KT transposed copy) ----------------
__global__ __launch_bounds__(256) void k1a_gemm(
    const float* __restrict__ Node,
    const float* __restrict__ Wq, const float* __restrict__ Wk,
    const float* __restrict__ Wv, const float* __restrict__ Wqv,
    const float* __restrict__ Wkv, const float* __restrict__ Wvv,
    float* __restrict__ ws)
{
    __shared__ float As[64][68];
    __shared__ float Bs[64][48];
    const int tid = threadIdx.x;
    const int cb = blockIdx.x % 24;
    const int l0 = (blockIdx.x / 24) * 64;
    const int col0 = cb * 48;

    const float* W; int nc, lc0;
    if (col0 < 192)      { W = Wq;  nc = 192; lc0 = col0; }
    else if (col0 < 384) { W = Wk;  nc = 192; lc0 = col0 - 192; }
    else if (col0 < 576) { W = Wv;  nc = 192; lc0 = col0 - 384; }
    else if (col0 < 720) { W = Wqv; nc = 144; lc0 = col0 - 576; }
    else if (col0 < 864) { W = Wkv; nc = 144; lc0 = col0 - 720; }
    else                 { W = Wvv; nc = 288; lc0 = col0 - 864; }

    const int tx = tid & 15, ty = tid >> 4;
    float acc[4][3];
#pragma unroll
    for (int r = 0; r < 4; ++r)
#pragma unroll
        for (int c = 0; c < 3; ++c) acc[r][c] = 0.f;

    for (int kc = 0; kc < 6; ++kc) {
        __syncthreads();
#pragma unroll
        for (int pass = 0; pass < 4; ++pass) {
            int m = (tid >> 4) + pass * 16;
            int kk = (tid & 15) * 4;
            const float4 a = *(const float4*)(Node + (size_t)(l0 + m) * CN + kc * 64 + kk);
            As[kk + 0][m] = a.x; As[kk + 1][m] = a.y;
            As[kk + 2][m] = a.z; As[kk + 3][m] = a.w;
        }
#pragma unroll
        for (int p = 0; p < 12; ++p) {
            int idx = p * 256 + tid;
            int kk = idx / 48, c = idx - kk * 48;
            Bs[kk][c] = W[(size_t)(kc * 64 + kk) * nc + lc0 + c];
        }
        __syncthreads();
#pragma unroll 8
        for (int kk = 0; kk < 64; ++kk) {
            const float4 av = *(const float4*)&As[kk][tx * 4];
            const float b0 = Bs[kk][ty * 3 + 0];
            const float b1 = Bs[kk][ty * 3 + 1];
            const float b2 = Bs[kk][ty * 3 + 2];
            acc[0][0] = fmaf(av.x, b0, acc[0][0]); acc[0][1] = fmaf(av.x, b1, acc[0][1]); acc[0][2] = fmaf(av.x, b2, acc[0][2]);
            acc[1][0] = fmaf(av.y, b0, acc[1][0]); acc[1][1] = fmaf(av.y, b1, acc[1][1]); acc[1][2] = fmaf(av.y, b2, acc[1][2]);
            acc[2][0] = fmaf(av.z, b0, acc[2][0]); acc[2][1] = fmaf(av.z, b1, acc[2][1]); acc[2][2] = fmaf(av.z, b2, acc[2][2]);
            acc[3][0] = fmaf(av.w, b0, acc[3][0]); acc[3][1] = fmaf(av.w, b1, acc[3][1]); acc[3][2] = fmaf(av.w, b2, acc[3][2]);
        }
    }
    float* raw = ws + WS_RAW;
#pragma unroll
    for (int r = 0; r < 4; ++r)
#pragma unroll
        for (int c = 0; c < 3; ++c)
            raw[(size_t)(l0 + tx * 4 + r) * NPROJ + col0 + ty * 3 + c] = acc[r][c];
    if (col0 >= 192 && col0 < 384) {
#pragma unroll
        for (int r = 0; r < 4; ++r)
#pragma unroll
            for (int c = 0; c < 3; ++c)
                ws[WS_KT + (size_t)(col0 - 192 + ty * 3 + c) * LQ + l0 + tx * 4 + r] = acc[r][c];
    }
}

// ---------------- K1b: frame apply + point norms ----------------
__global__ __launch_bounds__(256) void k1b_vec(
    const float* __restrict__ rots, const float* __restrict__ trans,
    float* __restrict__ ws)
{
    __shared__ float sqbuf[96];
    const int tid = threadIdx.x;
    const int l = blockIdx.x;
    const float* raw = ws + WS_RAW + (size_t)l * NPROJ;

    if (tid < 192) {
        int src, pt, typ;
        if (tid < 48)      { typ = 0; pt = tid;      src = 576 + pt * 3; }
        else if (tid < 96) { typ = 1; pt = tid - 48; src = 720 + pt * 3; }
        else               { typ = 2; pt = tid - 96; src = 864 + pt * 3; }
        float v0 = raw[src], v1 = raw[src + 1], v2 = raw[src + 2];
        const float* R = rots + l * 9;
        float o0 = R[0] * v0 + R[1] * v1 + R[2] * v2 + trans[l * 3 + 0] * 0.1f;
        float o1 = R[3] * v0 + R[4] * v1 + R[5] * v2 + trans[l * 3 + 1] * 0.1f;
        float o2 = R[6] * v0 + R[7] * v1 + R[8] * v2 + trans[l * 3 + 2] * 0.1f;
        if (typ == 0) {
            float* dst = ws + WS_QVG + (size_t)l * 144 + pt * 3;
            dst[0] = o0; dst[1] = o1; dst[2] = o2;
        } else if (typ == 1) {
            ws[WS_KVT + (size_t)(pt * 3 + 0) * LQ + l] = o0;
            ws[WS_KVT + (size_t)(pt * 3 + 1) * LQ + l] = o1;
            ws[WS_KVT + (size_t)(pt * 3 + 2) * LQ + l] = o2;
        } else {
            float* dst = ws + WS_VVG + (size_t)l * 288 + pt * 3;
            dst[0] = o0; dst[1] = o1; dst[2] = o2;
        }
        if (tid < 96) sqbuf[tid] = o0 * o0 + o1 * o1 + o2 * o2;
    }
    __syncthreads();
    if (tid < 24) {
        int typ = tid / 12, g = tid % 12;
        int b = typ * 48 + g * 4;
        float s = sqbuf[b] + sqbuf[b + 1] + sqbuf[b + 2] + sqbuf[b + 3];
        if (typ == 0) ws[WS_QN + (size_t)l * 12 + g] = s;
        else          ws[WS_KNT + (size_t)g * LQ + l] = s;
    }
}

// ---------------- K2a: base logits -> LGS ----------------
__global__ __launch_bounds__(256) void k2a_logits(
    const float* __restrict__ gamma, float* __restrict__ ws)
{
    __shared__ float cgls[NG];
    const int tid = threadIdx.x;
    const int i = blockIdx.x >> 1;
    const int h = blockIdx.x & 1;
    const int j = h * 256 + tid;

    if (tid < NG)
        cgls[tid] = log1pf(__expf(gamma[tid])) * 0.11785113019775793f;
    __syncthreads();

    const float* qrow  = ws + WS_RAW + (size_t)i * NPROJ;
    const float* qvrow = ws + WS_QVG + (size_t)i * 144;
    const float* qnrow = ws + WS_QN  + (size_t)i * NG;
    const float* KT  = ws + WS_KT;
    const float* KVT = ws + WS_KVT;
    const float* KNT = ws + WS_KNT;
    float lgs[NG];
#pragma unroll
    for (int g = 0; g < NG; ++g) {
        float qk = 0.f;
#pragma unroll
        for (int u = 0; u < PPG; ++u)
            qk = fmaf(qrow[g * PPG + u], KT[(size_t)(g * PPG + u) * LQ + j], qk);
        float dt = 0.f;
#pragma unroll
        for (int u = 0; u < 12; ++u)
            dt = fmaf(qvrow[g * 12 + u], KVT[(size_t)(g * 12 + u) * LQ + j], dt);
        float sq = qnrow[g] + KNT[(size_t)g * LQ + j] - 2.f * dt;
        lgs[g] = qk * 0.25f - cgls[g] * sq;
    }
    float4* dst = (float4*)(ws + WS_LGS + ((size_t)i * LQ + j) * NG);
    float4 s0, s1, s2;
    s0.x = lgs[0]; s0.y = lgs[1]; s0.z = lgs[2];  s0.w = lgs[3];
    s1.x = lgs[4]; s1.y = lgs[5]; s1.z = lgs[6];  s1.w = lgs[7];
    s2.x = lgs[8]; s2.y = lgs[9]; s2.z = lgs[10]; s2.w = lgs[11];
    dst[0] = s0; dst[1] = s1; dst[2] = s2;
}

// ---------------- K2b: bias pass, double-buffered, + softmax -> ATT_T ----------------
__global__ __launch_bounds__(256, 2) void k2b_bias(
    const float* __restrict__ Edge, const float* __restrict__ Wbias,
    float* __restrict__ ws)
{
    __shared__ float et[2][256 * 33];   // 67.6 KB double buffer
    __shared__ float red[4][NG];
    const int tid = threadIdx.x;
    const int i = blockIdx.x >> 1;
    const int h = blockIdx.x & 1;
    const int j = h * 256 + tid;
    const int jr = tid >> 3, c4s = tid & 7;   // staging coords (8 f4/row-pass)

    // base logits from LGS
    float lgs[NG];
    {
        const float4* lg4 = (const float4*)(ws + WS_LGS + ((size_t)i * LQ + j) * NG);
        float4 L0 = lg4[0], L1 = lg4[1], L2 = lg4[2];
        lgs[0] = L0.x; lgs[1] = L0.y; lgs[2] = L0.z;  lgs[3] = L0.w;
        lgs[4] = L1.x; lgs[5] = L1.y; lgs[6] = L1.z;  lgs[7] = L1.w;
        lgs[8] = L2.x; lgs[9] = L2.y; lgs[10] = L2.z; lgs[11] = L2.w;
    }

    const float4* e4 = (const float4*)Edge + ((size_t)i * LQ + h * 256) * 32;
    float4 buf[8];

    // prologue: load + write chunk 0
#pragma unroll
    for (int kk = 0; kk < 8; ++kk) {
        int idx = kk * 256 + tid;
        buf[kk] = e4[(size_t)(idx >> 3) * 32 + (idx & 7)];
    }
#pragma unroll
    for (int kk = 0; kk < 8; ++kk) {
        int idx = kk * 256 + tid;
        float* d = et[0] + (idx >> 3) * 33 + (idx & 7) * 4;
        d[0] = buf[kk].x; d[1] = buf[kk].y; d[2] = buf[kk].z; d[3] = buf[kk].w;
    }
    __syncthreads();

    for (int ch = 0; ch < 4; ++ch) {
        if (ch < 3) {
#pragma unroll
            for (int kk = 0; kk < 8; ++kk) {
                int idx = kk * 256 + tid;
                buf[kk] = e4[(size_t)(idx >> 3) * 32 + (ch + 1) * 8 + (idx & 7)];
            }
        }
        const float* wbch = Wbias + ch * 32 * NG;   // uniform -> s_load
        const float* r0 = et[ch & 1] + tid * 33;
#pragma unroll 4
        for (int c = 0; c < 32; ++c) {
            float e0 = r0[c];
            const float* wb = wbch + c * NG;
#pragma unroll
            for (int g = 0; g < NG; ++g) lgs[g] = fmaf(e0, wb[g], lgs[g]);
        }
        if (ch < 3) {
#pragma unroll
            for (int kk = 0; kk < 8; ++kk) {
                int idx = kk * 256 + tid;
                float* d = et[(ch + 1) & 1] + (idx >> 3) * 33 + (idx & 7) * 4;
                d[0] = buf[kk].x; d[1] = buf[kk].y; d[2] = buf[kk].z; d[3] = buf[kk].w;
            }
        }
        __syncthreads();
    }

    // partial softmax over this block's 256 keys
    const int wid = tid >> 6, lane = tid & 63;
    float pm[NG];
#pragma unroll
    for (int g = 0; g < NG; ++g) pm[g] = lgs[g];
#pragma unroll
    for (int g = 0; g < NG; ++g)
        for (int off = 1; off < 64; off <<= 1)
            pm[g] = fmaxf(pm[g], __shfl_xor(pm[g], off));
    if (lane == 0) {
#pragma unroll
        for (int g = 0; g < NG; ++g) red[wid][g] = pm[g];
    }
    __syncthreads();
    float gm[NG];
#pragma unroll
    for (int g = 0; g < NG; ++g)
        gm[g] = fmaxf(fmaxf(red[0][g], red[1][g]), fmaxf(red[2][g], red[3][g]));
    if (tid < NG)
        ws[WS_PM + ((size_t)i * 2 + h) * NG + tid] =
            fmaxf(fmaxf(red[0][tid], red[1][tid]), fmaxf(red[2][tid], red[3][tid]));
    __syncthreads();

    float ps[NG];
#pragma unroll
    for (int g = 0; g < NG; ++g) {
        float e = __expf(WLs * (lgs[g] - gm[g]));
        lgs[g] = e;
        ps[g] = e;
    }
#pragma unroll
    for (int g = 0; g < NG; ++g)
        for (int off = 1; off < 64; off <<= 1)
            ps[g] += __shfl_xor(ps[g], off);
    if (lane == 0) {
#pragma unroll
        for (int g = 0; g < NG; ++g) red[wid][g] = ps[g];
    }
    __syncthreads();
    if (tid < NG)
        ws[WS_PS + ((size_t)i * 2 + h) * NG + tid] =
            red[0][tid] + red[1][tid] + red[2][tid] + red[3][tid];

    // store transposed: ATT_T[i][g][j]
    float* attT = ws + WS_ATT + (size_t)i * (NG * LQ);
#pragma unroll
    for (int g = 0; g < NG; ++g) attT[g * LQ + j] = lgs[g];
}

// ---------------- K3a: O_Edge (single Edge stream, b128 at-reads) ----------------
__global__ __launch_bounds__(256) void k3a_oedge(
    const float* __restrict__ Edge, float* __restrict__ ws)
{
    __shared__ float atls[NG * 516];          // 24.8 KB scaled attention, padded rows
    __shared__ float bufA[4][32][NG][4];      // 24.6 KB
    __shared__ float sc[2][NG];
    const int tid = threadIdx.x;
    const int qi = blockIdx.x;

    if (tid < 24) {
        int hh = tid / NG, g = tid % NG;
        float m0 = ws[WS_PM + ((size_t)qi * 2 + 0) * NG + g];
        float m1 = ws[WS_PM + ((size_t)qi * 2 + 1) * NG + g];
        float ss0 = ws[WS_PS + ((size_t)qi * 2 + 0) * NG + g];
        float ss1 = ws[WS_PS + ((size_t)qi * 2 + 1) * NG + g];
        float m = fmaxf(m0, m1);
        float e0 = __expf(WLs * (m0 - m));
        float e1 = __expf(WLs * (m1 - m));
        float denom = ss0 * e0 + ss1 * e1;
        sc[hh][g] = (hh ? e1 : e0) / denom;
    }
    __syncthreads();

    // stage scaled at_T
    const float4* attT4 = (const float4*)(ws + WS_ATT + (size_t)qi * (NG * LQ));
#pragma unroll
    for (int m = 0; m < 6; ++m) {
        int idx = m * 256 + tid;              // 0..1535
        int g = idx >> 7, j4 = idx & 127;
        float s = sc[j4 >> 6][g];
        float4 v = attT4[g * 128 + j4];
        v.x *= s; v.y *= s; v.z *= s; v.w *= s;
        *(float4*)&atls[g * 516 + j4 * 4] = v;
    }
    __syncthreads();

    // Phase A: wave w covers j in [w*128, w*128+128), lane = (jh, c4)
    const int w = tid >> 6, lane = tid & 63, jh = lane >> 5, c4 = lane & 31;
    float acc[NG][4];
#pragma unroll
    for (int g = 0; g < NG; ++g)
#pragma unroll
        for (int r = 0; r < 4; ++r) acc[g][r] = 0.f;
    const float4* e4 = (const float4*)(Edge + (size_t)qi * LQ * CE);
    for (int s = 0; s < 16; ++s) {
        int j0 = w * 128 + jh * 64 + s * 4;
        float4 e0 = e4[(size_t)(j0 + 0) * 32 + c4];
        float4 e1 = e4[(size_t)(j0 + 1) * 32 + c4];
        float4 e2 = e4[(size_t)(j0 + 2) * 32 + c4];
        float4 e3 = e4[(size_t)(j0 + 3) * 32 + c4];
#pragma unroll
        for (int g = 0; g < NG; ++g) {
            float4 a = *(const float4*)&atls[g * 516 + j0];
            acc[g][0] = fmaf(a.x, e0.x, fmaf(a.y, e1.x, fmaf(a.z, e2.x, fmaf(a.w, e3.x, acc[g][0]))));
            acc[g][1] = fmaf(a.x, e0.y, fmaf(a.y, e1.y, fmaf(a.z, e2.y, fmaf(a.w, e3.y, acc[g][1]))));
            acc[g][2] = fmaf(a.x, e0.z, fmaf(a.y, e1.z, fmaf(a.z, e2.z, fmaf(a.w, e3.z, acc[g][2]))));
            acc[g][3] = fmaf(a.x, e0.w, fmaf(a.y, e1.w, fmaf(a.z, e2.w, fmaf(a.w, e3.w, acc[g][3]))));
        }
    }
#pragma unroll
    for (int g = 0; g < NG; ++g)
#pragma unroll
        for (int r = 0; r < 4; ++r) acc[g][r] += __shfl_xor(acc[g][r], 32);
    if (jh == 0) {
#pragma unroll
        for (int g = 0; g < NG; ++g)
#pragma unroll
            for (int r = 0; r < 4; ++r) bufA[w][c4][g][r] = acc[g][r];
    }
    __syncthreads();
    float* feat = ws + WS_FEAT + (size_t)qi * FEAT;
    for (int m = 0; m < 6; ++m) {
        int o = tid + m * 256;
        int g = o >> 7, c = o & 127;
        int cc4 = c >> 2, r = c & 3;
        feat[o] = bufA[0][cc4][g][r] + bufA[1][cc4][g][r] +
                  bufA[2][cc4][g][r] + bufA[3][cc4][g][r];
    }
}

// ---------------- K3b: O_Node / O_vec / O_norm ----------------
__global__ __launch_bounds__(256) void k3b_rest(
    const float* __restrict__ rots, const float* __restrict__ trans,
    float* __restrict__ ws)
{
    __shared__ float atls[NG * 516];
    __shared__ float sc[2][NG];
    __shared__ float ovecl[240];
    const int tid = threadIdx.x;
    const int qi = blockIdx.x >> 1;
    const int s  = blockIdx.x & 1;

    if (tid < 24) {
        int hh = tid / NG, g = tid % NG;
        float m0 = ws[WS_PM + ((size_t)qi * 2 + 0) * NG + g];
        float m1 = ws[WS_PM + ((size_t)qi * 2 + 1) * NG + g];
        float ss0 = ws[WS_PS + ((size_t)qi * 2 + 0) * NG + g];
        float ss1 = ws[WS_PS + ((size_t)qi * 2 + 1) * NG + g];
        float m = fmaxf(m0, m1);
        float e0 = __expf(WLs * (m0 - m));
        float e1 = __expf(WLs * (m1 - m));
        float denom = ss0 * e0 + ss1 * e1;
        sc[hh][g] = (hh ? e1 : e0) / denom;
    }
    __syncthreads();

    const float4* attT4 = (const float4*)(ws + WS_ATT + (size_t)qi * (NG * LQ));
#pragma unroll
    for (int m = 0; m < 6; ++m) {
        int idx = m * 256 + tid;
        int g = idx >> 7, j4 = idx & 127;
        float f = sc[j4 >> 6][g];
        float4 v = attT4[g * 128 + j4];
        v.x *= f; v.y *= f; v.z *= f; v.w *= f;
        *(float4*)&atls[g * 516 + j4 * 4] = v;
    }
    __syncthreads();

    float* feat = ws + WS_FEAT + (size_t)qi * FEAT;
    const float* raw = ws + WS_RAW;
    const float* vvg = ws + WS_VVG;
    if (tid < 240) {
        if (s == 0 && tid < 192) {
            int g = tid >> 4;
            const float* arow = atls + g * 516;
            float sum = 0.f;
            for (int j4 = 0; j4 < 128; ++j4) {
                float4 a = *(const float4*)&arow[j4 * 4];
                int j = j4 * 4;
                sum = fmaf(a.x, raw[(size_t)(j + 0) * NPROJ + 384 + tid], sum);
                sum = fmaf(a.y, raw[(size_t)(j + 1) * NPROJ + 384 + tid], sum);
                sum = fmaf(a.z, raw[(size_t)(j + 2) * NPROJ + 384 + tid], sum);
                sum = fmaf(a.w, raw[(size_t)(j + 3) * NPROJ + 384 + tid], sum);
            }
            feat[1536 + tid] = sum;
        } else {
            int u = (s == 0) ? (tid - 192) : (48 + tid);
            int lidx = (s == 0) ? (tid - 192) : tid;
            int g = u / 24;
            const float* arow = atls + g * 516;
            float sum = 0.f;
            for (int j4 = 0; j4 < 128; ++j4) {
                float4 a = *(const float4*)&arow[j4 * 4];
                int j = j4 * 4;
                sum = fmaf(a.x, vvg[(size_t)(j + 0) * 288 + u], sum);
                sum = fmaf(a.y, vvg[(size_t)(j + 1) * 288 + u], sum);
                sum = fmaf(a.z, vvg[(size_t)(j + 2) * 288 + u], sum);
                sum = fmaf(a.w, vvg[(size_t)(j + 3) * 288 + u], sum);
            }
            ovecl[lidx] = sum;
        }
    }
    __syncthreads();

    int npts = (s == 0) ? 16 : 80;
    if (tid < npts) {
        int P = (s == 0) ? tid : (16 + tid);
        int u0l = (s == 0) ? (P * 3) : (P * 3 - 48);
        const float* R = rots + qi * 9;
        float t0 = trans[qi * 3 + 0] * 0.1f;
        float t1 = trans[qi * 3 + 1] * 0.1f;
        float t2 = trans[qi * 3 + 2] * 0.1f;
        float d0 = ovecl[u0l + 0] - t0;
        float d1 = ovecl[u0l + 1] - t1;
        float d2 = ovecl[u0l + 2] - t2;
        float o0 = R[0] * d0 + R[3] * d1 + R[6] * d2;
        float o1 = R[1] * d0 + R[4] * d1 + R[7] * d2;
        float o2 = R[2] * d0 + R[5] * d1 + R[8] * d2;
        feat[1728 + P * 3 + 0] = o0;
        feat[1728 + P * 3 + 1] = o1;
        feat[1728 + P * 3 + 2] = o2;
        feat[2016 + P] = sqrtf(o0 * o0 + o1 * o1 + o2 * o2 + 1e-8f);
    }
}

// ---------------- K4: feat @ Wout — LDS-tiled GEMM, split-K x3 ----------------
__global__ __launch_bounds__(256) void k4_gemm(const float* __restrict__ Wout,
                                               float* __restrict__ ws)
{
    __shared__ float As[64][68];
    __shared__ float Bs[64][48];
    const int tid = threadIdx.x;
    const int cc = blockIdx.x >> 6;
    const int t  = blockIdx.x & 63;
    const int l0 = (t >> 3) * 64;
    const int col0 = (t & 7) * 48;
    const float* feat = ws + WS_FEAT;

    const int tx = tid & 15, ty = tid >> 4;
    float acc[4][3];
#pragma unroll
    for (int r = 0; r < 4; ++r)
#pragma unroll
        for (int c = 0; c < 3; ++c) acc[r][c] = 0.f;

    for (int kc = cc * 11; kc < cc * 11 + 11; ++kc) {
        __syncthreads();
#pragma unroll
        for (int pass = 0; pass < 4; ++pass) {
            int m = (tid >> 4) + pass * 16;
            int kk = (tid & 15) * 4;
            const float4 a = *(const float4*)(feat + (size_t)(l0 + m) * FEAT + kc * 64 + kk);
            As[kk + 0][m] = a.x; As[kk + 1][m] = a.y;
            As[kk + 2][m] = a.z; As[kk + 3][m] = a.w;
        }
#pragma unroll
        for (int p = 0; p < 12; ++p) {
            int idx = p * 256 + tid;
            int kk = idx / 48, c = idx - kk * 48;
            Bs[kk][c] = Wout[(size_t)(kc * 64 + kk) * CN + col0 + c];
        }
        __syncthreads();
#pragma unroll 8
        for (int kk = 0; kk < 64; ++kk) {
            const float4 av = *(const float4*)&As[kk][tx * 4];
            const float b0 = Bs[kk][ty * 3 + 0];
            const float b1 = Bs[kk][ty * 3 + 1];
            const float b2 = Bs[kk][ty * 3 + 2];
            acc[0][0] = fmaf(av.x, b0, acc[0][0]); acc[0][1] = fmaf(av.x, b1, acc[0][1]); acc[0][2] = fmaf(av.x, b2, acc[0][2]);
            acc[1][0] = fmaf(av.y, b0, acc[1][0]); acc[1][1] = fmaf(av.y, b1, acc[1][1]); acc[1][2] = fmaf(av.y, b2, acc[1][2]);
            acc[2][0] = fmaf(av.z, b0, acc[2][0]); acc[2][1] = fmaf(av.z, b1, acc[2][1]); acc[2][2] = fmaf(av.z, b2, acc[2][2]);
            acc[3][0] = fmaf(av.w, b0, acc[3][0]); acc[3][1] = fmaf(av.w, b1, acc[3][1]); acc[3][2] = fmaf(av.w, b2, acc[3][2]);
        }
    }
    float* part = ws + WS_PART + (size_t)cc * LQ * CN;
#pragma unroll
    for (int r = 0; r < 4; ++r)
#pragma unroll
        for (int c = 0; c < 3; ++c)
            part[(size_t)(l0 + tx * 4 + r) * CN + col0 + ty * 3 + c] = acc[r][c];
}

// ---------------- K5: reduce partials + bias ----------------
__global__ __launch_bounds__(384) void k5_red(const float* __restrict__ bout,
                                              const float* __restrict__ wsc,
                                              float* __restrict__ out)
{
    const int i = blockIdx.x, n = threadIdx.x;
    const float* part = wsc + WS_PART;
    size_t idx = (size_t)i * CN + n;
    size_t st = (size_t)LQ * CN;
    out[idx] = part[idx] + part[st + idx] + part[2 * st + idx] + bout[n];
}

extern "C" void kernel_launch(void* const* d_in, const int* in_sizes, int n_in,
                              void* d_out, int out_size, void* d_ws, size_t ws_size,
                              hipStream_t stream) {
    const float* Node  = (const float*)d_in[0];
    const float* Edge  = (const float*)d_in[1];
    const float* rots  = (const float*)d_in[2];
    const float* trans = (const float*)d_in[3];
    const float* Wq    = (const float*)d_in[4];
    const float* Wk    = (const float*)d_in[5];
    const float* Wv    = (const float*)d_in[6];
    const float* Wqv   = (const float*)d_in[7];
    const float* Wkv   = (const float*)d_in[8];
    const float* Wvv   = (const float*)d_in[9];
    const float* Wbias = (const float*)d_in[10];
    const float* gamma = (const float*)d_in[11];
    const float* Wout  = (const float*)d_in[12];
    const float* bout  = (const float*)d_in[13];
    float* ws = (float*)d_ws;

    k1a_gemm<<<192, 256, 0, stream>>>(Node, Wq, Wk, Wv, Wqv, Wkv, Wvv, ws);
    k1b_vec<<<512, 256, 0, stream>>>(rots, trans, ws);
    k2a_logits<<<1024, 256, 0, stream>>>(gamma, ws);
    k2b_bias<<<1024, 256, 0, stream>>>(Edge, Wbias, ws);
    k3a_oedge<<<512, 256, 0, stream>>>(Edge, ws);
    k3b_rest<<<1024, 256, 0, stream>>>(rots, trans, ws);
    k4_gemm<<<192, 256, 0, stream>>>(Wout, ws);
    k5_red<<<512, 384, 0, stream>>>(bout, ws, (float*)d_out);
}